// Round 2
// baseline (146.454 us; speedup 1.0000x reference)
//
#include <hip/hip_runtime.h>
#include <hip/hip_bf16.h>

// Causal linear attention, chunked decomposition.
// B=4 H=16 T=2048 D=64. Chunk C=256, NC=8 chunks, BH=64 batch-heads.
// Kernel 1: per-(bh,chunk) KV state  KV_c = K_c^T V_c  (64x64 fp32) -> ws
// Kernel 2: per-(bh,chunk) output    O = Q_c * prefixKV + tril(Q_c K_c^T) V_c
// bf16 MFMA (16x16x32), fp32 accumulate. Threshold 36.96 >> bf16 error (~3).
//
// R2: occupancy fix for the latency-bound attn kernel.
//  - attn: 512 threads / 8 waves per block (grid stays 512 = 2 blocks/CU)
//    -> 16 waves/CU instead of 8. Each wave owns M-tiles {w, 15-w}: exactly
//    5 (j,tile) MFMA pairs per wave (uniform, no barrier imbalance).
//  - Per-wave register state halves (qf 2x2, acc 2x4) -> fits the 128-VGPR
//    cap of __launch_bounds__(512,4) without spill.
//  - Keeps R1 structure: S^T via swapped MFMA operands (wave-private Sw, no
//    block barriers), vectorized LDS staging, dbuf + issue-early/write-late,
//    1 barrier per key subtile (4 total).
//  - kv kernel unchanged (already near its ~11 us read floor).

#define B_   4
#define H_   16
#define T_   2048
#define D_   64
#define BH_  64
#define CCH  256
#define NCH  8
#define LPAD 8
#define LW   (D_ + LPAD)   // 72 bf16 = 144 B row stride (16B aligned; rotates
                           // 16B blocks across rows -> b128 reads ~conflict-free)

typedef __bf16 bf16x4 __attribute__((ext_vector_type(4)));
typedef __bf16 bf16x8 __attribute__((ext_vector_type(8)));
typedef float  f32x2  __attribute__((ext_vector_type(2)));
typedef float  f32x4  __attribute__((ext_vector_type(4)));

// MFMA fragment layouts (16x16x32 bf16, HW-verified per guide):
//   A: A[m = lane&15][k = (lane>>4)*8 + j]   (8 contiguous k per lane)
//   B: B[k = (lane>>4)*8 + j][n = lane&15]
//   C/D: row = (lane>>4)*4 + reg, col = lane&15
// Mirror property: a row-major contiguous 8-elem load of X rows is both the
// A-fragment of X and the B-fragment of X^T.

__global__ __launch_bounds__(256, 2) void kv_chunk_kernel(
    const float* __restrict__ k, const float* __restrict__ v,
    float* __restrict__ kvws) {
  __shared__ __align__(16) __bf16 KT[2][D_][LW];  // [d][s] transposed, dbuf
  __shared__ __align__(16) __bf16 VT[2][D_][LW];  // [d][s] transposed, dbuf

  const int tid  = threadIdx.x;
  const int lane = tid & 63;
  const int w    = tid >> 6;
  const int quad = lane >> 4;
  const int l15  = lane & 15;
  const int bh   = blockIdx.x >> 3;
  const int c    = blockIdx.x & (NCH - 1);
  const long base = ((long)bh * T_ + (long)c * CCH) * D_;

  // 4x4 register-transpose staging: thread (s4,d4) owns a 4x4 tile.
  const int s4 = tid >> 4;   // 0..15 -> s-block of 4
  const int d4 = tid & 15;   // 0..15 -> d-block of 4

  f32x4 kreg[4], vreg[4];
  const float* kp0 = k + base + (long)(s4 * 4) * D_ + d4 * 4;
  const float* vp0 = v + base + (long)(s4 * 4) * D_ + d4 * 4;

  auto LOAD = [&](int st) {
#pragma unroll
    for (int r = 0; r < 4; ++r) {
      kreg[r] = *(const f32x4*)(kp0 + (long)(st * 64 + r) * D_);
      vreg[r] = *(const f32x4*)(vp0 + (long)(st * 64 + r) * D_);
    }
  };
  auto WRITE = [&](int p) {
#pragma unroll
    for (int cc2 = 0; cc2 < 4; ++cc2) {
      bf16x4 ka, va;
#pragma unroll
      for (int r = 0; r < 4; ++r) {
        ka[r] = (__bf16)kreg[r][cc2];
        va[r] = (__bf16)vreg[r][cc2];
      }
      *(bf16x4*)&KT[p][d4 * 4 + cc2][s4 * 4] = ka;
      *(bf16x4*)&VT[p][d4 * 4 + cc2][s4 * 4] = va;
    }
  };

  const f32x4 vzero = {0.f, 0.f, 0.f, 0.f};
  f32x4 acc[4];
#pragma unroll
  for (int n = 0; n < 4; ++n) acc[n] = vzero;

  LOAD(0);
  WRITE(0);
  __syncthreads();
  for (int st = 0; st < 4; ++st) {  // 4 s-tiles of 64 cover the 256 chunk
    const int p = st & 1;
    if (st < 3) LOAD(st + 1);  // issue early; write after compute
    // KV[d1][d2] += sum_s K[s][d1]*V[s][d2]; wave w owns d1 rows [16w,16w+16)
#pragma unroll
    for (int ks = 0; ks < 2; ++ks) {
      bf16x8 a = *(const bf16x8*)&KT[p][w * 16 + l15][ks * 32 + quad * 8];
#pragma unroll
      for (int n = 0; n < 4; ++n) {
        bf16x8 b = *(const bf16x8*)&VT[p][n * 16 + l15][ks * 32 + quad * 8];
        acc[n] = __builtin_amdgcn_mfma_f32_16x16x32_bf16(a, b, acc[n], 0, 0, 0);
      }
    }
    if (st < 3) {
      WRITE(p ^ 1);
      __syncthreads();
    }
  }
  float* out = kvws + ((long)blockIdx.x << 12);  // 64*64 fp32 per (bh,c)
#pragma unroll
  for (int n = 0; n < 4; ++n)
#pragma unroll
    for (int rr = 0; rr < 4; ++rr)
      out[(w * 16 + quad * 4 + rr) * 64 + n * 16 + l15] = acc[n][rr];
}

__global__ __launch_bounds__(512, 4) void attn_chunk_kernel(
    const float* __restrict__ q, const float* __restrict__ k,
    const float* __restrict__ v, const float* __restrict__ kvws,
    float* __restrict__ out) {
  __shared__ __align__(16) __bf16 KVT[D_][LW];     // KVsum transposed [d2][d1]
  __shared__ __align__(16) __bf16 Kj[2][64][LW];   // key subtile [s][d], dbuf
  __shared__ __align__(16) __bf16 VTj[2][D_][LW];  // value subtile [d][s], dbuf
  __shared__ __align__(16) __bf16 Sw[8][16][LW];   // per-wave S tile [s][q]->[m][s]
  // total LDS: 9216 + 18432 + 18432 + 18432 = 64512 B (fits 64KB static limit,
  // 2 blocks/CU -> 129 KB of 160 KB)

  const int tid  = threadIdx.x;
  const int lane = tid & 63;
  const int w    = tid >> 6;        // 0..7
  const int quad = lane >> 4;
  const int l15  = lane & 15;
  const int bh   = blockIdx.x >> 3;
  const int c    = blockIdx.x & (NCH - 1);
  const long base = ((long)bh * T_ + (long)c * CCH) * D_;

  // staging thread mappings (512 threads)
  const int slK = tid >> 3;          // K: row 0..63
  const int d0K = (tid & 7) * 8;     // K: 8 cols per thread
  const int sV  = (tid >> 5) * 4;    // V: s-block of 4 (0,4,..,60)
  const int dV  = (tid & 31) * 2;    // V: 2 cols per thread

  f32x4 kreg0, kreg1;
  f32x2 vreg[4];
  auto LOADJ = [&](int j) {
    const float* kp = k + base + (long)(j * 64 + slK) * D_ + d0K;
    const float* vp = v + base + (long)(j * 64 + sV) * D_ + dV;
    kreg0 = *(const f32x4*)(kp);
    kreg1 = *(const f32x4*)(kp + 4);
#pragma unroll
    for (int r = 0; r < 4; ++r) vreg[r] = *(const f32x2*)(vp + (long)r * D_);
  };
  auto WRITEJ = [&](int p) {
    bf16x8 kb;
#pragma unroll
    for (int e = 0; e < 4; ++e) {
      kb[e]     = (__bf16)kreg0[e];
      kb[4 + e] = (__bf16)kreg1[e];
    }
    *(bf16x8*)&Kj[p][slK][d0K] = kb;
#pragma unroll
    for (int e = 0; e < 2; ++e) {
      bf16x4 va;
#pragma unroll
      for (int r = 0; r < 4; ++r) va[r] = (__bf16)vreg[r][e];
      *(bf16x4*)&VTj[p][dV + e][sV] = va;
    }
  };

  // ---- 1. prefix-sum KV states of prior chunks -> KVT (bf16, transposed)
  // thread owns linear range [tid*8, tid*8+8): contiguous dwordx4 loads.
  float kvacc[8];
#pragma unroll
  for (int i = 0; i < 8; ++i) kvacc[i] = 0.f;
  const float* wsbh = kvws + ((long)(bh * NCH) << 12);
  for (int cc = 0; cc < c; ++cc) {
    const float* pp = wsbh + ((long)cc << 12) + tid * 8;
#pragma unroll
    for (int x = 0; x < 2; ++x) {
      f32x4 t = *(const f32x4*)(pp + x * 4);
#pragma unroll
      for (int e = 0; e < 4; ++e) kvacc[x * 4 + e] += t[e];
    }
  }
  {
    const int d1  = tid >> 3;          // lin = tid*8+ii: d1 = lin>>6
    const int d2b = (tid & 7) * 8;     //                 d2 = d2b+ii
#pragma unroll
    for (int ii = 0; ii < 8; ++ii) KVT[d2b + ii][d1] = (__bf16)kvacc[ii];
  }

  // ---- 2. Q A-fragments. wave w owns M-tiles {w, 15-w} (uniform 5 MFMA
  // pairs/wave across the causal triangle).
  bf16x8 qf[2][2];
#pragma unroll
  for (int t = 0; t < 2; ++t) {
    const int m = t ? (15 - w) : w;
    const int row = m * 16 + l15;
    const float* qp = q + base + (long)row * D_ + quad * 8;
#pragma unroll
    for (int ks = 0; ks < 2; ++ks) {
      f32x4 lo = *(const f32x4*)(qp + ks * 32);
      f32x4 hi = *(const f32x4*)(qp + ks * 32 + 4);
      bf16x8 f;
#pragma unroll
      for (int e = 0; e < 4; ++e) {
        f[e]     = (__bf16)lo[e];
        f[4 + e] = (__bf16)hi[e];
      }
      qf[t][ks] = f;
    }
  }

  const f32x4 vzero = {0.f, 0.f, 0.f, 0.f};
  f32x4 acc[2][4];
#pragma unroll
  for (int t = 0; t < 2; ++t)
#pragma unroll
    for (int n = 0; n < 4; ++n) acc[t][n] = vzero;

  LOADJ(0);
  WRITEJ(0);
  __syncthreads();  // KVT + tile-0 staging ready
  LOADJ(1);         // prefetch j=1 under the inter-chunk matmul

  // ---- 3. inter-chunk: O += Q @ KVsum   (zeros when c==0; uniform work)
#pragma unroll
  for (int ks = 0; ks < 2; ++ks)
#pragma unroll
    for (int n = 0; n < 4; ++n) {
      bf16x8 b = *(const bf16x8*)&KVT[n * 16 + l15][ks * 32 + quad * 8];
#pragma unroll
      for (int t = 0; t < 2; ++t)
        acc[t][n] =
            __builtin_amdgcn_mfma_f32_16x16x32_bf16(qf[t][ks], b, acc[t][n], 0, 0, 0);
    }

  // ---- 4. intra-chunk causal part over 4 key subtiles of 64
  for (int j = 0; j < 4; ++j) {
    const int p = j & 1;
#pragma unroll
    for (int t = 0; t < 2; ++t) {
      const int m = t ? (15 - w) : w;
      if (m >= 4 * j) {  // tile needs this key subtile (m>>2==j: diagonal)
        f32x4 s[4];
#pragma unroll
        for (int n = 0; n < 4; ++n) s[n] = vzero;
        // S^T = K Q^T: A = K-frag (row-major Kj), B = Q-frag (mirror prop).
        // C layout: s_in64 = n*16 + quad*4 + rr, q_local = l15.
#pragma unroll
        for (int ks = 0; ks < 2; ++ks)
#pragma unroll
          for (int n = 0; n < 4; ++n) {
            bf16x8 kf = *(const bf16x8*)&Kj[p][n * 16 + l15][ks * 32 + quad * 8];
            s[n] = __builtin_amdgcn_mfma_f32_16x16x32_bf16(kf, qf[t][ks], s[n],
                                                           0, 0, 0);
          }
        // mask + pack 4 contiguous s-values -> one b64 store per n
        // (wave-private Sw: intra-wave LDS ordering suffices, no barrier).
        const int mloc = (m & 3) * 16;
        const bool diag = ((m >> 2) == j);
#pragma unroll
        for (int n = 0; n < 4; ++n) {
          bf16x4 pk;
#pragma unroll
          for (int rr = 0; rr < 4; ++rr) {
            float val = s[n][rr];
            if (diag && (n * 16 + quad * 4 + rr > mloc + l15)) val = 0.f;
            pk[rr] = (__bf16)val;
          }
          *(bf16x4*)&Sw[w][l15][n * 16 + quad * 4] = pk;
        }
#pragma unroll
        for (int ks = 0; ks < 2; ++ks) {
          bf16x8 a = *(const bf16x8*)&Sw[w][l15][ks * 32 + quad * 8];
#pragma unroll
          for (int n = 0; n < 4; ++n) {
            bf16x8 vf = *(const bf16x8*)&VTj[p][n * 16 + l15][ks * 32 + quad * 8];
            acc[t][n] =
                __builtin_amdgcn_mfma_f32_16x16x32_bf16(a, vf, acc[t][n], 0, 0, 0);
          }
        }
      }
    }
    if (j < 3) {
      WRITEJ(p ^ 1);      // write-late into the idle buffer
      __syncthreads();    // single barrier per subtile
      if (j < 2) LOADJ(j + 2);  // issue-early next tile's loads
    }
  }

  // ---- 5. epilogue: write O (fp32)
  float* op = out + base;
#pragma unroll
  for (int t = 0; t < 2; ++t) {
    const int m = t ? (15 - w) : w;
    const int row = m * 16 + quad * 4;
#pragma unroll
    for (int n = 0; n < 4; ++n)
#pragma unroll
      for (int rr = 0; rr < 4; ++rr)
        op[(long)(row + rr) * D_ + n * 16 + l15] = acc[t][n][rr];
  }
}

extern "C" void kernel_launch(void* const* d_in, const int* in_sizes, int n_in,
                              void* d_out, int out_size, void* d_ws, size_t ws_size,
                              hipStream_t stream) {
  const float* q = (const float*)d_in[0];
  const float* k = (const float*)d_in[1];
  const float* v = (const float*)d_in[2];
  float* out = (float*)d_out;
  float* kvws = (float*)d_ws;  // needs BH_*NCH*64*64*4 = 8 MiB

  hipLaunchKernelGGL(kv_chunk_kernel, dim3(BH_ * NCH), dim3(256), 0, stream,
                     k, v, kvws);
  hipLaunchKernelGGL(attn_chunk_kernel, dim3(BH_ * NCH), dim3(512), 0, stream,
                     q, k, v, kvws, out);
}